// Round 12
// baseline (94.241 us; speedup 1.0000x reference)
//
#include <hip/hip_runtime.h>
#include <cfloat>

#define NS 7
#define NC 256
#define NH 64
#define NW 64
#define NR 128
#define RFL(x) __builtin_amdgcn_readfirstlane(x)

// ---------- A: CHW->HWC transpose, x16 internal replication (diagnostic) ----------
__global__ __launch_bounds__(256) void diag_transpose(
    const float* __restrict__ f, float* __restrict__ ft)
{
    __shared__ float tile[64][65];
    const int tid = threadIdx.x;
    const int b   = blockIdx.x & 255;   // 16 replicas of the 256-block grid
    const int h   = b >> 2;
    const int c0  = (b & 3) * 64;

    #pragma unroll
    for (int k = 0; k < 16; ++k) {
        int q = tid + k * 256;
        int c = q >> 6;
        int w = q & 63;
        tile[w][c] = f[(size_t)(c0 + c) * (NH * NW) + h * NW + w];
    }
    __syncthreads();
    #pragma unroll
    for (int k = 0; k < 16; ++k) {
        int q = tid + k * 256;
        int w = q >> 6;
        int c = q & 63;
        ft[(size_t)h * (NW * NC) + w * NC + c0 + c] = tile[w][c];
    }
}

// ---------- B: R4-champion LDS-plane pool, x2 internal replication ----------
#define RG 16
#define PR 68
#define PW 68
__global__ __launch_bounds__(256) void diag_ldsplane(
    const float* __restrict__ f,
    const int* __restrict__ rois,
    float* __restrict__ out)
{
    __shared__ float plane[PR][PW];

    const int tid = threadIdx.x;
    const int bb  = blockIdx.x & 2047;  // 2 replicas of the 2048-block grid
    const int c   = bb >> 3;
    const int g   = bb & 7;

    {
        const float4* src = (const float4*)(f + (size_t)c * (NH * NW));
        #pragma unroll
        for (int k = 0; k < 4; ++k) {
            int q  = tid + k * 256;
            int h  = q >> 4;
            int w4 = (q & 15) * 4;
            float4 v = src[q];
            *(float4*)&plane[h][w4] = v;
        }
    }
    __syncthreads();

    for (int o = tid; o < RG * NS * NS; o += 256) {
        int lr  = o / (NS * NS);
        int bin = o - lr * (NS * NS);
        int i   = bin / NS;
        int j   = bin - i * NS;
        int r   = g * RG + lr;

        int x1 = rois[4 * r + 0];
        int y1 = rois[4 * r + 1];
        int x2 = rois[4 * r + 2];
        int y2 = rois[4 * r + 3];
        int Lh = x2 - x1 + 1;
        int Lw = y2 - y1 + 1;

        int h0 = x1 + (i * Lh) / NS;
        int h1 = x1 + ((i + 1) * Lh + NS - 1) / NS;
        int w0 = y1 + (j * Lw) / NS;
        int w1 = y1 + ((j + 1) * Lw + NS - 1) / NS;

        float m = -FLT_MAX;
        for (int h = h0; h < h1; h += 4) {
            for (int w = w0; w < w1; w += 4) {
                float v[16];
                #pragma unroll
                for (int dh = 0; dh < 4; ++dh)
                    #pragma unroll
                    for (int dw = 0; dw < 4; ++dw)
                        v[dh * 4 + dw] = plane[h + dh][w + dw];
                #pragma unroll
                for (int dh = 0; dh < 4; ++dh)
                    #pragma unroll
                    for (int dw = 0; dw < 4; ++dw) {
                        bool ok = (h + dh < h1) && (w + dw < w1);
                        m = fmaxf(m, ok ? v[dh * 4 + dw] : -FLT_MAX);
                    }
            }
        }

        out[((size_t)(r * NC + c)) * (NS * NS) + bin] = m;
    }
}

// ---------- C: R10 HWC-scalar pool, x2 internal replication (final write) ----------
__global__ __launch_bounds__(256, 4) void diag_hwcpool(
    const float* __restrict__ ft, const int* __restrict__ rois,
    float* __restrict__ out)
{
    const int lane = threadIdx.x & 63;
    int bx = blockIdx.x;
    if (bx >= 3136) bx -= 3136;         // 2 replicas
    const int Wv = RFL(bx * 4 + (threadIdx.x >> 6));

    const int cg  = Wv & 1;
    const int t   = Wv >> 1;
    const int bin = t % (NS * NS);
    const int r   = t / (NS * NS);
    const int i   = bin / NS;
    const int j   = bin - i * NS;

    const int x1 = RFL(rois[4 * r + 0]);
    const int y1 = RFL(rois[4 * r + 1]);
    const int x2 = RFL(rois[4 * r + 2]);
    const int y2 = RFL(rois[4 * r + 3]);
    const int Lh = x2 - x1 + 1;
    const int Lw = y2 - y1 + 1;

    const int h0 = x1 + (i * Lh) / NS;
    const int h1 = x1 + ((i + 1) * Lh + NS - 1) / NS;
    const int w0 = y1 + (j * Lw) / NS;
    const int w1 = y1 + ((j + 1) * Lw + NS - 1) / NS;
    const int sph = h1 - h0;
    const int spw = w1 - w0;

    const float* base = ft + cg * 128 + lane * 2;

    float2 acc = make_float2(-FLT_MAX, -FLT_MAX);

    if (sph <= 2 && spw <= 2) {
        const int hB = min(h0 + 1, h1 - 1);
        const int wB = min(w0 + 1, w1 - 1);
        float2 v0 = *(const float2*)(base + (size_t)(h0 * NW + w0) * NC);
        float2 v1 = *(const float2*)(base + (size_t)(h0 * NW + wB) * NC);
        float2 v2 = *(const float2*)(base + (size_t)(hB * NW + w0) * NC);
        float2 v3 = *(const float2*)(base + (size_t)(hB * NW + wB) * NC);
        acc.x = fmaxf(fmaxf(v0.x, v1.x), fmaxf(v2.x, v3.x));
        acc.y = fmaxf(fmaxf(v0.y, v1.y), fmaxf(v2.y, v3.y));
    } else {
        for (int a = 0; a < sph; a += 4) {
            for (int b = 0; b < spw; b += 4) {
                #pragma unroll
                for (int dh = 0; dh < 4; ++dh) {
                    const int h = min(h0 + a + dh, h1 - 1);
                    #pragma unroll
                    for (int dw = 0; dw < 4; ++dw) {
                        const int w = min(w0 + b + dw, w1 - 1);
                        float2 v = *(const float2*)(base + (size_t)(h * NW + w) * NC);
                        acc.x = fmaxf(acc.x, v.x);
                        acc.y = fmaxf(acc.y, v.y);
                    }
                }
            }
        }
    }

    const int c = cg * 128 + lane * 2;
    float* op = out + ((size_t)r * NC + c) * (NS * NS) + bin;
    op[0]       = acc.x;
    op[NS * NS] = acc.y;
}

extern "C" void kernel_launch(void* const* d_in, const int* in_sizes, int n_in,
                              void* d_out, int out_size, void* d_ws, size_t ws_size,
                              hipStream_t stream)
{
    const float* feature_map = (const float*)d_in[0];
    const int*   rois        = (const int*)d_in[1];
    float*       out         = (float*)d_out;
    float*       ft          = (float*)d_ws;   // 4 MB HWC scratch

    // A: transpose, x16 replication (visible in top-5)
    diag_transpose<<<256 * 16, 256, 0, stream>>>(feature_map, ft);
    // B: R4 LDS-plane pool, x2 replication (writes correct output)
    diag_ldsplane<<<2048 * 2, 256, 0, stream>>>(feature_map, rois, out);
    // C: R10 HWC pool, x2 replication (writes correct output last)
    diag_hwcpool<<<3136 * 2, 256, 0, stream>>>(ft, rois, out);
}